// Round 10
// baseline (965.331 us; speedup 1.0000x reference)
//
#include <hip/hip_runtime.h>
#include <hip/hip_bf16.h>

#define BB 2
#define TT 2048
#define DD 1024
#define HH 8
#define HKk 512
#define BTt 4096   // BB*TT
#define CC 16      // chunk length
#define NT 128     // tiles per bh
#define PREPSZ 4608  // floats per (bh,tile) prep block (18 KiB)
// prep layout: K1 0 | Q1 1024 | KH2 2048 | BV 3072 | A15 4096 | GW 4160 | pad->4608

typedef unsigned short u16;
typedef __attribute__((ext_vector_type(8))) short bf16x8;
typedef __attribute__((ext_vector_type(4))) float f32x4;

__device__ __forceinline__ u16 f2bf(float v) {
  union { float f; unsigned u; } c; c.f = v;
  return (u16)((c.u + 0x7fffu + ((c.u >> 16) & 1u)) >> 16);  // RNE
}
__device__ __forceinline__ float bf2f(u16 v) {
  union { unsigned u; float f; } c; c.u = ((unsigned)v) << 16; return c.f;
}
__device__ __forceinline__ float sigm(float x) { return 1.f / (1.f + expf(-x)); }

// DPP lane exchange on the VALU pipe (no DS). Within each 16-lane row:
//   0xB1 = quad_perm[1,0,3,2]  (exact xor1)
//   0x4E = quad_perm[2,3,0,1]  (exact xor2)
//   0x141 = row_half_mirror    (side-crossing bijection for the "xor4" stage)
//   0x128 = row_ror:8          (exact xor8: (i+8)%16 == i^8)
template <int CTRL>
__device__ __forceinline__ float dppx(float x) {
  union { float f; int i; } c; c.f = x;
  c.i = __builtin_amdgcn_update_dpp(c.i, c.i, CTRL, 0xf, 0xf, false);
  return c.f;
}

// async global->LDS, 16B per lane; dest = lds_base + lane*16 (wave-linear)
__device__ __forceinline__ void gld16(const u16* g, u16* l) {
  __builtin_amdgcn_global_load_lds((const __attribute__((address_space(1))) void*)g,
                                   (__attribute__((address_space(3))) void*)l, 16, 0, 0);
}

// ---------- batched weight transpose + cast ----------
// dst[(n*rs+ro)*K + k] = f2bf(src[k*N+n]) for 8 jobs in one launch.
struct TransJobs {
  const float* src[8];
  u16* dst[8];
  int K[8], N[8], rs[8], ro[8], lognx[8];
  int off[8];  // block-offset of each job (ascending)
};
__global__ __launch_bounds__(256) void ktransB(TransJobs J) {
  __shared__ u16 t[32][33];
  int bid = blockIdx.x;
  int j = 0;
#pragma unroll
  for (int q = 1; q < 8; q++) j += (bid >= J.off[q]) ? 1 : 0;
  int local = bid - J.off[j];
  const float* src = J.src[j];
  u16* dst = J.dst[j];
  int K = J.K[j], N = J.N[j], rs = J.rs[j], ro = J.ro[j];
  int nxm = (1 << J.lognx[j]) - 1;
  int n0 = (local & nxm) * 32, k0 = (local >> J.lognx[j]) * 32;
  int tx = threadIdx.x & 31, ty0 = threadIdx.x >> 5;
#pragma unroll
  for (int i = 0; i < 32; i += 8)
    t[ty0 + i][tx] = f2bf(src[(size_t)(k0 + ty0 + i) * N + n0 + tx]);
  __syncthreads();
#pragma unroll
  for (int i = 0; i < 32; i += 8)
    dst[((size_t)(n0 + ty0 + i) * rs + ro) * K + k0 + tx] = t[tx][ty0 + i];
}

// ---------- RMS norm over 1024 cols ----------
__global__ __launch_bounds__(256) void krms(const float* __restrict__ x,
                                            const float* __restrict__ w,
                                            void* __restrict__ out, int obf) {
  size_t row = blockIdx.x;
  __shared__ float red[4];
  float vals[4];
  float s = 0.f;
#pragma unroll
  for (int i = 0; i < 4; i++) {
    vals[i] = x[row * DD + threadIdx.x + i * 256];
    s += vals[i] * vals[i];
  }
#pragma unroll
  for (int off = 32; off; off >>= 1) s += __shfl_xor(s, off);
  if ((threadIdx.x & 63) == 0) red[threadIdx.x >> 6] = s;
  __syncthreads();
  float tot = red[0] + red[1] + red[2] + red[3];
  float sc = rsqrtf(tot * (1.f / DD) + 1e-6f);
#pragma unroll
  for (int i = 0; i < 4; i++) {
    size_t idx = row * DD + threadIdx.x + i * 256;
    float vv = vals[i] * sc * w[threadIdx.x + i * 256];
    if (obf) ((u16*)out)[idx] = f2bf(vv);
    else ((float*)out)[idx] = vv;
  }
}

// ---------- causal depthwise conv (KW=4) + bias + SiLU: f32 -> bf16 ----------
__global__ __launch_bounds__(256) void kconv(const float* __restrict__ hin,
                                             const float* __restrict__ cw,
                                             const float* __restrict__ cb,
                                             u16* __restrict__ hout) {
  size_t i = (size_t)blockIdx.x * 256 + threadIdx.x;
  int d = (int)(i & 1023);
  int bt = (int)(i >> 10);
  int b = bt >> 11, t = bt & 2047;
  float acc = cb[d];
#pragma unroll
  for (int j = 0; j < 4; j++) {
    int tt = t - 3 + j;
    if (tt >= 0) acc += hin[(((size_t)(b * TT + tt)) << 10) + d] * cw[d * 4 + j];
  }
  hout[i] = f2bf(acc * sigm(acc));
}

// ---------- small f32-compute GEMM (64x64 tiles) ----------
__global__ __launch_bounds__(256) void kgemm(const void* __restrict__ A, int abf,
                                             const float* __restrict__ Bm,
                                             const float* __restrict__ bias,
                                             float* __restrict__ C,
                                             int M, int N, int K, int act) {
  __shared__ __align__(16) float As[16][64];
  __shared__ __align__(16) float Bs[16][64];
  int tid = threadIdx.x;
  int tx = tid & 15, ty = tid >> 4;
  int row0 = blockIdx.y * 64, col0 = blockIdx.x * 64;
  float acc[4][4] = {};
  for (int k0 = 0; k0 < K; k0 += 16) {
#pragma unroll
    for (int l = 0; l < 4; l++) {
      int e = tid * 4 + l;
      int m = e >> 4, kk = e & 15;
      int gr = row0 + m;
      size_t ai = (size_t)gr * K + k0 + kk;
      As[kk][m] = (gr < M) ? (abf ? bf2f(((const u16*)A)[ai]) : ((const float*)A)[ai]) : 0.f;
    }
#pragma unroll
    for (int l = 0; l < 4; l++) {
      int e = tid + l * 256;
      int kk = e >> 6, n = e & 63;
      int gc = col0 + n;
      Bs[kk][n] = (gc < N) ? Bm[(size_t)(k0 + kk) * N + gc] : 0.f;
    }
    __syncthreads();
#pragma unroll
    for (int kk = 0; kk < 16; kk++) {
      float4 av = *(const float4*)&As[kk][ty * 4];
      float4 bv = *(const float4*)&Bs[kk][tx * 4];
      float a[4] = {av.x, av.y, av.z, av.w};
      float b[4] = {bv.x, bv.y, bv.z, bv.w};
#pragma unroll
      for (int i = 0; i < 4; i++)
#pragma unroll
        for (int j = 0; j < 4; j++) acc[i][j] += a[i] * b[j];
    }
    __syncthreads();
  }
#pragma unroll
  for (int i = 0; i < 4; i++) {
    int r = row0 + ty * 4 + i;
    if (r >= M) continue;
#pragma unroll
    for (int j = 0; j < 4; j++) {
      int cc = col0 + tx * 4 + j;
      if (cc >= N) continue;
      float vv = acc[i][j];
      if (bias) vv += bias[cc];
      if (act == 1) vv = vv * sigm(vv);
      else if (act == 2) vv = sigm(vv);
      C[(size_t)r * N + cc] = vv;
    }
  }
}

// ---------- batched skinny-N GEMM: 3 jobs x 256 blocks, 16-row tiles ----------
struct SJobs {
  const void* A[3];
  const float* B[3];
  const float* bias[3];
  float* C[3];
  int N[3], act[3], abf[3];
};
__global__ __launch_bounds__(256) void kgemmS3(SJobs J) {
  __shared__ __align__(16) float As[32][17];
  __shared__ __align__(16) float Bs[32][64];
  int job = blockIdx.x >> 8;
  int row0 = (blockIdx.x & 255) << 4;
  const void* A = J.A[job];
  const float* Bm = J.B[job];
  int N = J.N[job], abf = J.abf[job], act = J.act[job];
  int tid = threadIdx.x;
  int tx = tid & 63;
  int ty = tid >> 6;
  float acc[4] = {};
  for (int k0 = 0; k0 < DD; k0 += 32) {
    __syncthreads();
#pragma unroll
    for (int l = 0; l < 2; l++) {
      int idx = tid * 2 + l;
      int k = idx & 31, m = idx >> 5;
      size_t ai = (size_t)(row0 + m) * DD + k0 + k;
      As[k][m] = abf ? bf2f(((const u16*)A)[ai]) : ((const float*)A)[ai];
    }
#pragma unroll
    for (int l = 0; l < 8; l++) {
      int idx = tid + l * 256;
      int n = idx & 63, k = idx >> 6;
      Bs[k][n] = (n < N) ? Bm[(size_t)(k0 + k) * N + n] : 0.f;
    }
    __syncthreads();
#pragma unroll
    for (int kk = 0; kk < 32; kk++) {
      float b = Bs[kk][tx];
#pragma unroll
      for (int i = 0; i < 4; i++) acc[i] += As[kk][ty * 4 + i] * b;
    }
  }
  if (tx < N) {
    float* C = J.C[job];
    const float* bias = J.bias[job];
#pragma unroll
    for (int i = 0; i < 4; i++) {
      float vv = acc[i] + bias[tx];
      if (act == 1) vv = vv * sigm(vv);
      C[(size_t)(row0 + ty * 4 + i) * N + tx] = vv;
    }
  }
}

// ---------- big MFMA GEMM: global_load_lds staging + XOR-swizzled LDS ----------
// EPI: 0 = f32 store | 1 = interleaved SwiGLU -> bf16 | 2 = g1+v*g2 | 3 = f1+v
//      4 = f32 store with per-64-col L2-normalize on cols<1024 (QKVD q|k)
template <int EPI>
__global__ __launch_bounds__(256) void kmfma(
    const u16* __restrict__ A, int lda, const u16* __restrict__ Bt,
    void* __restrict__ C, int ldc, int M, int N, int K,
    const float* __restrict__ g1f, const float* __restrict__ g2f,
    const float* __restrict__ f1) {
  __shared__ __align__(16) u16 As[128 * 64];
  __shared__ __align__(16) u16 Bs[128 * 64];
  int tid = threadIdx.x;
  int lane = tid & 63, wv = tid >> 6;
  int m0 = (wv & 1) * 64, n0 = (wv >> 1) * 64;
  int ml = lane & 15, kq = (lane >> 4) << 3;
  // XCD-aware block swizzle (grid sizes are all %8==0): contiguous work chunks
  // per XCD so neighboring tiles share L2-resident panels.
  int nbx = gridDim.x;
  int flat = blockIdx.y * nbx + blockIdx.x;
  int nwg = nbx * gridDim.y;
  int work = (flat & 7) * (nwg >> 3) + (flat >> 3);
  int row0 = (work / nbx) * 128, col0 = (work % nbx) * 128;
  int lrow = lane >> 3;             // 0..7 within 8-row band
  int lslot = (lane & 7) ^ lrow;    // pre-swizzled source 16B-slot

  f32x4 acc[4][4];
#pragma unroll
  for (int i = 0; i < 4; i++)
#pragma unroll
    for (int j = 0; j < 4; j++) acc[i][j] = (f32x4){0.f, 0.f, 0.f, 0.f};

  for (int k0 = 0; k0 < K; k0 += 64) {
    __syncthreads();
#pragma unroll
    for (int j = 0; j < 4; j++) {
      int r0 = j * 32 + wv * 8;
      gld16(&A[(size_t)(row0 + r0 + lrow) * lda + k0 + lslot * 8], &As[r0 * 64]);
      gld16(&Bt[(size_t)(col0 + r0 + lrow) * K + k0 + lslot * 8], &Bs[r0 * 64]);
    }
    __syncthreads();
#pragma unroll
    for (int kk = 0; kk < 64; kk += 32) {
      int sw = (((kk + kq) >> 3) ^ (ml & 7)) << 3;
      bf16x8 af[4], bfr[4];
#pragma unroll
      for (int i = 0; i < 4; i++)
        af[i] = *(const bf16x8*)&As[(m0 + i * 16 + ml) * 64 + sw];
#pragma unroll
      for (int j = 0; j < 4; j++)
        bfr[j] = *(const bf16x8*)&Bs[(n0 + j * 16 + ml) * 64 + sw];
#pragma unroll
      for (int i = 0; i < 4; i++)
#pragma unroll
        for (int j = 0; j < 4; j++)
          acc[i][j] = __builtin_amdgcn_mfma_f32_16x16x32_bf16(af[i], bfr[j], acc[i][j], 0, 0, 0);
    }
  }
  int rbase = row0 + m0 + ((lane >> 4) << 2);
  if (EPI == 4) {
    // q|k L2-normalize: each wave's 64-col span == one head's dk group.
    int donorm = (col0 + n0) < 1024;
#pragma unroll
    for (int i = 0; i < 4; i++) {
#pragma unroll
      for (int r = 0; r < 4; r++) {
        float s = 0.f;
#pragma unroll
        for (int j = 0; j < 4; j++) { float v = acc[i][j][r]; s += v * v; }
#pragma unroll
        for (int off = 1; off < 16; off <<= 1) s += __shfl_xor(s, off);
        float sc = donorm ? 1.f / (sqrtf(s) + 1e-6f) : 1.f;
        int gr = rbase + i * 16 + r;
#pragma unroll
        for (int j = 0; j < 4; j++) {
          int gc = col0 + n0 + j * 16 + ml;
          ((float*)C)[(size_t)gr * ldc + gc] = acc[i][j][r] * sc;
        }
      }
    }
    return;
  }
#pragma unroll
  for (int i = 0; i < 4; i++) {
#pragma unroll
    for (int j = 0; j < 4; j++) {
      int gc = col0 + n0 + j * 16 + ml;
#pragma unroll
      for (int r = 0; r < 4; r++) {
        int gr = rbase + i * 16 + r;
        float v = acc[i][j][r];
        if (EPI == 0) {
          ((float*)C)[(size_t)gr * ldc + gc] = v;
        } else if (EPI == 1) {
          // interleaved SwiGLU: even col = Wff1 (silu), odd col = Wff3.
          float p = __shfl_xor(v, 1);
          float a0 = (lane & 1) ? p : v;
          float b0 = (lane & 1) ? v : p;
          float g = a0 * sigm(a0) * b0;
          if (!(lane & 1))
            ((u16*)C)[(size_t)gr * ldc + (gc >> 1)] = f2bf(g);
        } else if (EPI == 2) {
          size_t idx = (size_t)gr * ldc + gc;
          ((float*)C)[idx] = g1f[idx] + v * g2f[idx];
        } else {
          size_t idx = (size_t)gr * ldc + gc;
          ((float*)C)[idx] = f1[idx] + v;
        }
      }
    }
  }
}

// ---------- headwise RMS norm: yat f32 -> bf16 ----------
__global__ __launch_bounds__(256) void kheadnorm(const float* __restrict__ y,
                                                 const float* __restrict__ hw,
                                                 u16* __restrict__ yo) {
  int lane = threadIdx.x & 63;
  size_t r = (size_t)blockIdx.x * 4 + (threadIdx.x >> 6);
  int h = (int)(r & 7);
  float vv = y[r * 64 + lane];
  float s = vv * vv;
#pragma unroll
  for (int off = 32; off; off >>= 1) s += __shfl_xor(s, off);
  yo[r * 64 + lane] = f2bf(vv * rsqrtf(s * (1.f / 64.f) + 1e-6f) * hw[h * 64 + lane]);
}

// ---------- klifA: membrane recurrence only -> packed spike bitmasks ----------
__global__ __launch_bounds__(64) void klifA(const float* __restrict__ dr, int drs,
                                            unsigned* __restrict__ masks) {
  int bh = blockIdx.x;
  int b = bh >> 3, h = bh & 7;
  int lane = threadIdx.x;
  float cur[32], nxt[32];
#pragma unroll
  for (int i = 0; i < 32; i++)
    cur[i] = dr[(size_t)(b * TT + i) * drs + h * 64 + lane];
  float mem = 0.f;
  for (int t0 = 0; t0 < TT; t0 += 32) {
    if (t0 + 32 < TT) {
#pragma unroll
      for (int i = 0; i < 32; i++)
        nxt[i] = dr[(size_t)(b * TT + t0 + 32 + i) * drs + h * 64 + lane];
    }
    unsigned m = 0;
#pragma unroll
    for (int i = 0; i < 32; i++) {
      mem = 0.9f * mem + cur[i];
      int s = (mem > 0.5f) ? 1 : 0;
      mem -= s ? 0.5f : 0.f;
      m |= ((unsigned)s) << i;
    }
    masks[((size_t)bh * 64 + (t0 >> 5)) * 64 + lane] = m;
#pragma unroll
    for (int i = 0; i < 32; i++) cur[i] = nxt[i];
  }
}

// ---------- kprep: chunk C=16 UT-transform precompute + fused LIF gates ----------
// klifB fused in: per t, spike bit from masks, __ballot over the 64 k-lanes
// for `active`, 6-shuffle reduce for the beta term. bet[] is wave-uniform;
// lane 0 writes sBeta with STATIC indices (rule #20: no dynamic reg indexing).
// LDS leading dim padded 64->68: phase-2 reads sKiP[s2][k] across the 16 s2
// lanes hit banks (s2*4+k)%32 -> 2-way max (was 16-way at stride 64).
__global__ __launch_bounds__(64) void kprep(const float* __restrict__ X1,
                                            const float* __restrict__ ab,
                                            const float* __restrict__ bb,
                                            const float* __restrict__ asp,
                                            const float* __restrict__ bsp,
                                            const unsigned* __restrict__ masks,
                                            float* __restrict__ prep) {
  int blk = blockIdx.x;          // 16 bh * 128 tiles
  int bh = blk >> 7, T = blk & 127;
  int b = bh >> 3, h = bh & 7;
  int lane = threadIdx.x;
  size_t row0 = (size_t)(b * TT) + (size_t)T * CC;
  float* out = prep + (size_t)blk * PREPSZ;
  __shared__ float sKP[CC][68], sKiP[CC][68], sQP[CC][68];
  __shared__ float sBC[CC * CC], sG[CC * CC], sW[CC * CC], sBeta[CC];

  float aspk = asp[h * 64 + lane];
  float bspk = bsp[h * 64 + lane];
  float Pt[CC], kv[CC], kh[CC], bet[CC];
  {
    float P = 1.f;
#pragma unroll
    for (int t = 0; t < CC; t++) {
      size_t rt = row0 + t;
      int tg = T * CC + t;
      unsigned mw = masks[((size_t)bh * 64 + (tg >> 5)) * 64 + lane];
      int s = (mw >> (tg & 31)) & 1;
      unsigned long long act = __ballot(s != 0);
      float sp = (float)s;
      float abv = ab[rt * HKk + h * 64 + lane];
      int active = (act != 0ull);
      float a = active ? sigm(abv + aspk * sp) : 1.f;
      float r2 = sp * bspk;
#pragma unroll
      for (int off = 32; off; off >>= 1) r2 += __shfl_xor(r2, off);
      float bbv = bb[rt * HH + h];
      bet[t] = active ? sigm(bbv + r2) : 0.f;
      kv[t] = X1[rt * 2048 + h * 64 + 512 + lane];
      float qv = X1[rt * 2048 + h * 64 + lane];
      P *= a;
      Pt[t] = P;
      float qp = qv * P;
      sQP[t][lane] = qp;
      out[1024 + t * 64 + lane] = qp;  // Q1
    }
    float PC = Pt[CC - 1];
#pragma unroll
    for (int t = 0; t < CC; t++) {
      float KiPv = kv[t] / Pt[t];
      sKP[t][lane] = kv[t] * Pt[t];
      sKiP[t][lane] = KiPv;
      kh[t] = PC * KiPv;
    }
    out[4096 + lane] = PC;  // A15
  }
  if (lane == 0) {
#pragma unroll
    for (int t = 0; t < CC; t++) sBeta[t] = bet[t];
  }
  __syncthreads();
#pragma unroll
  for (int t = 0; t < CC; t++) out[t * 64 + lane] = bet[t] * kv[t] * Pt[t];  // K1

  // phase 2: 256 (t,s) pairs, 4 per lane
#pragma unroll
  for (int i = 0; i < 4; i++) {
    int p = lane + 64 * i;
    int t2 = p >> 4, s2 = p & 15;
    float ac = 0.f, ag = 0.f;
#pragma unroll
    for (int k = 0; k < 64; k++) {
      float kip = sKiP[s2][k];
      ac += sKP[t2][k] * kip;
      ag += sQP[t2][k] * kip;
    }
    sBC[p] = (t2 > s2) ? sBeta[t2] * ac : 0.f;
    sG[p] = (t2 >= s2) ? ag : 0.f;
    sW[p] = 0.f;
  }
  __syncthreads();
  if (lane < CC) sW[lane * CC + lane] = 1.f;
  __syncthreads();

  // phase 3a: W = (I + strictlower(BC))^{-1}, forward substitution
  for (int t = 1; t < CC; t++) {
    if (lane < t) {
      float a = -sBC[t * CC + lane];
      for (int s = lane + 1; s < t; s++) a -= sBC[t * CC + s] * sW[s * CC + lane];
      sW[t * CC + lane] = a;
    }
    __syncthreads();
  }
  // phase 3b: GW = G * W (lower incl diag), 4 entries per lane
#pragma unroll
  for (int i = 0; i < 4; i++) {
    int p = lane + 64 * i;
    int t2 = p >> 4, s2 = p & 15;
    float gw = 0.f;
    if (s2 <= t2)
      for (int m = s2; m <= t2; m++) gw += sG[t2 * CC + m] * sW[m * CC + s2];
    out[4160 + p] = gw;
  }
  // phase 4: KH2_r = sum_{s>=r} kh_s * W[s][r]   (lane = k)
#pragma unroll
  for (int r = 0; r < CC; r++) {
    float acc = 0.f;
    for (int s = r; s < CC; s++) acc += kh[s] * sW[s * CC + r];
    out[2048 + r * 64 + lane] = acc;
  }
  // phase 5: BV_t = beta_t * v_t
#pragma unroll
  for (int t = 0; t < CC; t++)
    out[3072 + t * 64 + lane] = bet[t] * X1[(row0 + t) * 2048 + h * 64 + 1024 + lane];
}

// ---------- kscan2 v8: DPP walker + barrier-free LDS ping-pong prefetch ----------
// v5 structure (256 single-wave blocks, DPP exchanges) + K1/Q1 staged through
// LDS. Single wave => NO barriers; DS ops are program-ordered via lgkmcnt.
// The ds_write of the prefetched registers at tile end FORCES the global loads
// to complete there (a store is not rematerializable — r8's reg-pin failed
// because reg values are). Global K1/Q1 loads are 4x-deduplicated (v5 loaded
// identical data in all 4 vv-groups); LDS reads broadcast across vv-groups
// (same-address => no conflict; across kp: 2-way, free).
// [r5/r9 lessons: more waves/CU don't help — per-tile L2-latency-stall-bound.]
__global__ __launch_bounds__(64, 1) void kscan2(const float* __restrict__ prep,
                                                float* __restrict__ y) {
  int bid = blockIdx.x;
  int bh = bid & 15, vg = bid >> 4;
  int b = bh >> 3, h = bh & 7;
  int lane = threadIdx.x;
  int kp = lane & 15, vv = lane >> 4;
  const float* base = prep + (size_t)bh * NT * PREPSZ;
  __shared__ __align__(16) float lbuf[2][2048];   // [buf][K1(1024)|Q1(1024)]

  float4 S = make_float4(0.f, 0.f, 0.f, 0.f);
  float4 gk[4], gq[4];
  // prologue: tile 0 K1/Q1 -> lbuf[0] (global->reg->ds_write)
#pragma unroll
  for (int r = 0; r < 4; r++) {
    gk[r] = *(const float4*)(base + r * 256 + lane * 4);
    gq[r] = *(const float4*)(base + 1024 + r * 256 + lane * 4);
  }
#pragma unroll
  for (int r = 0; r < 4; r++) {
    *(float4*)&lbuf[0][r * 256 + lane * 4] = gk[r];
    *(float4*)&lbuf[0][1024 + r * 256 + lane * 4] = gq[r];
  }
  // prefetch tile 1 into regs
#pragma unroll
  for (int r = 0; r < 4; r++) {
    gk[r] = *(const float4*)(base + PREPSZ + r * 256 + lane * 4);
    gq[r] = *(const float4*)(base + PREPSZ + 1024 + r * 256 + lane * 4);
  }
  size_t yb = (size_t)(b * TT) * HKk + h * 64 + vg * 4 + vv;

  for (int T = 0; T < NT; T++) {
    const float* bp = base + (size_t)T * PREPSZ;
    const float* lb = lbuf[T & 1];
    // tail loads, earliest consumer first (bvs -> gw -> a15 -> kh2)
    float4 kh2[16], gw[4], a15;
    float bvs;
    bvs = bp[3072 + kp * 64 + vg * 4 + vv];
#pragma unroll
    for (int i = 0; i < 4; i++)
      gw[i] = *(const float4*)(bp + 4160 + kp * 16 + i * 4);
    a15 = *(const float4*)(bp + 4096 + kp * 4);
#pragma unroll
    for (int r = 0; r < CC; r++)
      kh2[r] = *(const float4*)(bp + 2048 + r * 64 + kp * 4);
    // dot from LDS (tile T staged last iteration; no exposed global latency)
    float bt[16], qb[16];
#pragma unroll
    for (int t = 0; t < CC; t++) {
      float4 kvv = *(const float4*)&lb[t * 64 + kp * 4];
      float4 qvv = *(const float4*)&lb[1024 + t * 64 + kp * 4];
      bt[t] = kvv.x * S.x + kvv.y * S.y + kvv.z * S.z + kvv.w * S.w;
      qb[t] = qvv.x * S.x + qvv.y * S.y + qvv.z * S.z + qvv.w * S.w;
    }
    // reduce-scatter bt: lane kp -> full bt[kp] (DPP stages 8,hm,2,1)
    float b8[8], b4[4], b2[2], bS;
#pragma unroll
    for (int j = 0; j < 8; j++) {
      float snd = (kp & 8) ? bt[j] : bt[j + 8];
      float rcv = dppx<0x128>(snd);
      b8[j] = ((kp & 8) ? bt[j + 8] : bt[j]) + rcv;
    }
#pragma unroll
    for (int j = 0; j < 4; j++) {
      float snd = (kp & 4) ? b8[j] : b8[j + 4];
      float rcv = dppx<0x141>(snd);
      b4[j] = ((kp & 4) ? b8[j + 4] : b8[j]) + rcv;
    }
#pragma unroll
    for (int j = 0; j < 2; j++) {
      float snd = (kp & 2) ? b4[j] : b4[j + 2];
      float rcv = dppx<0x4E>(snd);
      b2[j] = ((kp & 2) ? b4[j + 2] : b4[j]) + rcv;
    }
    {
      float snd = (kp & 1) ? b2[0] : b2[1];
      float rcv = dppx<0xB1>(snd);
      bS = ((kp & 1) ? b2[1] : b2[0]) + rcv;
    }
    float uS = bvs - bS;
    // all-gather uS -> u[0..15] in natural order (DPP stages 1,2,hm,8)
    float u[16];
    {
      float g = dppx<0xB1>(uS);
      float a0 = (kp & 1) ? g : uS, a1 = (kp & 1) ? uS : g;
      float g0 = dppx<0x4E>(a0), g1 = dppx<0x4E>(a1);
      float c0 = (kp & 2) ? g0 : a0, c1 = (kp & 2) ? g1 : a1;
      float c2 = (kp & 2) ? a0 : g0, c3 = (kp & 2) ? a1 : g1;
      float h0 = dppx<0x141>(c0), h1 = dppx<0x141>(c1);
      float h2 = dppx<0x141>(c2), h3 = dppx<0x141>(c3);
      float d0 = (kp & 4) ? h0 : c0, d1 = (kp & 4) ? h1 : c1;
      float d2 = (kp & 4) ? h2 : c2, d3 = (kp & 4) ? h3 : c3;
      float d4 = (kp & 4) ? c0 : h0, d5 = (kp & 4) ? c1 : h1;
      float d6 = (kp & 4) ? c2 : h2, d7 = (kp & 4) ? c3 : h3;
      float e0 = dppx<0x128>(d0), e1 = dppx<0x128>(d1);
      float e2 = dppx<0x128>(d2), e3 = dppx<0x128>(d3);
      float e4 = dppx<0x128>(d4), e5 = dppx<0x128>(d5);
      float e6 = dppx<0x128>(d6), e7 = dppx<0x128>(d7);
      u[0] = (kp & 8) ? e0 : d0; u[1] = (kp & 8) ? e1 : d1;
      u[2] = (kp & 8) ? e2 : d2; u[3] = (kp & 8) ? e3 : d3;
      u[4] = (kp & 8) ? e4 : d4; u[5] = (kp & 8) ? e5 : d5;
      u[6] = (kp & 8) ? e6 : d6; u[7] = (kp & 8) ? e7 : d7;
      u[8] = (kp & 8) ? d0 : e0; u[9] = (kp & 8) ? d1 : e1;
      u[10] = (kp & 8) ? d2 : e2; u[11] = (kp & 8) ? d3 : e3;
      u[12] = (kp & 8) ? d4 : e4; u[13] = (kp & 8) ? d5 : e5;
      u[14] = (kp & 8) ? d6 : e6; u[15] = (kp & 8) ? d7 : e7;
    }
    // reduce-scatter qb -> qsel = full qb[kp] (DPP)
    float p8[8], p4[4], p2[2], qsel;
#pragma unroll
    for (int j = 0; j < 8; j++) {
      float snd = (kp & 8) ? qb[j] : qb[j + 8];
      float rcv = dppx<0x128>(snd);
      p8[j] = ((kp & 8) ? qb[j + 8] : qb[j]) + rcv;
    }
#pragma unroll
    for (int j = 0; j < 4; j++) {
      float snd = (kp & 4) ? p8[j] : p8[j + 4];
      float rcv = dppx<0x141>(snd);
      p4[j] = ((kp & 4) ? p8[j + 4] : p8[j]) + rcv;
    }
#pragma unroll
    for (int j = 0; j < 2; j++) {
      float snd = (kp & 2) ? p4[j] : p4[j + 2];
      float rcv = dppx<0x4E>(snd);
      p2[j] = ((kp & 2) ? p4[j + 2] : p4[j]) + rcv;
    }
    {
      float snd = (kp & 1) ? p2[0] : p2[1];
      float rcv = dppx<0xB1>(snd);
      qsel = ((kp & 1) ? p2[1] : p2[0]) + rcv;
    }
    // output row t=kp (GW upper triangle is zero from kprep)
    float o = qsel;
#pragma unroll
    for (int i = 0; i < 4; i++)
      o += gw[i].x * u[i * 4] + gw[i].y * u[i * 4 + 1] +
           gw[i].z * u[i * 4 + 2] + gw[i].w * u[i * 4 + 3];
    y[yb + (size_t)(T * CC + kp) * HKk] = o;
    // state update: S = A15 .* S + sum_r KH2[r] * u[r]
    S.x *= a15.x; S.y *= a15.y; S.z *= a15.z; S.w *= a15.w;
#pragma unroll
    for (int r = 0; r < CC; r++) {
      S.x += kh2[r].x * u[r]; S.y += kh2[r].y * u[r];
      S.z += kh2[r].z * u[r]; S.w += kh2[r].w * u[r];
    }
    // stage T+1 into the other buffer (vmcnt drain lands HERE, after compute;
    // a store cannot be sunk/rematerialized), then issue T+2 loads.
    if (T < NT - 1) {
      float* nb = lbuf[(T + 1) & 1];
#pragma unroll
      for (int r = 0; r < 4; r++) {
        *(float4*)&nb[r * 256 + lane * 4] = gk[r];
        *(float4*)&nb[1024 + r * 256 + lane * 4] = gq[r];
      }
      if (T + 2 < NT) {
        const float* np2 = base + (size_t)(T + 2) * PREPSZ;
#pragma unroll
        for (int r = 0; r < 4; r++) {
          gk[r] = *(const float4*)(np2 + r * 256 + lane * 4);
          gq[r] = *(const float4*)(np2 + 1024 + r * 256 + lane * 4);
        }
      }
    }
  }
}

extern "C" void kernel_launch(void* const* d_in, const int* in_sizes, int n_in,
                              void* d_out, int out_size, void* d_ws, size_t ws_size,
                              hipStream_t stream) {
  const float *x = (const float*)d_in[0], *norm_in_w = (const float*)d_in[1],
              *conv_w = (const float*)d_in[2], *conv_b = (const float*)d_in[3],
              *Wq = (const float*)d_in[4], *Wk = (const float*)d_in[5],
              *Wv = (const float*)d_in[6], *Wo = (const float*)d_in[7],
              *Wspike = (const float*)d_in[8], *Wau = (const float*)d_in[9],
              *bau = (const float*)d_in[10], *Wad = (const float*)d_in[11],
              *bad_ = (const float*)d_in[12], *asp = (const float*)d_in[13],
              *Wbeta = (const float*)d_in[14], *bbeta = (const float*)d_in[15],
              *bsp = (const float*)d_in[16], *hnw = (const float*)d_in[17],
              *Wu1 = (const float*)d_in[18], *bu1 = (const float*)d_in[19],
              *Wu2 = (const float*)d_in[20], *bu2 = (const float*)d_in[21],
              *ffw = (const float*)d_in[22], *Wff1 = (const float*)d_in[23],
              *Wff3 = (const float*)d_in[24], *Wff2 = (const float*)d_in[25];
  (void)in_sizes; (void)n_in; (void)out_size; (void)ws_size;

  char* wsb = (char*)d_ws;
  size_t off = 0;
  auto alloc = [&](size_t bytes) {
    void* p = wsb + off;
    off += (bytes + 255) & ~(size_t)255;
    return p;
  };
  float* h    = (float*)alloc((size_t)BTt * DD * 4);       // 16 MiB
  u16*   hc   = (u16*)alloc((size_t)BTt * DD * 2);         // 8
  size_t qoff = off;  // overlay region start (dead before FFN)
  float* X1   = (float*)alloc((size_t)BTt * 2048 * 4);     // 32  q|k|v|drive
  float* ab   = (float*)alloc((size_t)BTt * HKk * 4);      // 8
  float* au   = (float*)alloc((size_t)BTt * 64 * 4);       // 1
  float* bb   = (float*)alloc((size_t)BTt * HH * 4);       // .125
  float* u1   = (float*)alloc((size_t)BTt * 64 * 4);       // 1
  float* gate = (float*)alloc((size_t)BTt * DD * 4);       // 16
  float* yat  = (float*)alloc((size_t)BTt * HKk * 4);      // 8
  u16* yat_bf = (u16*)alloc((size_t)BTt * HKk * 2);        // 4
  u16* f_bf   = (u16*)(wsb + qoff);  // 32 MiB overlay over X1 (dead at FFN)
  float* y2   = (float*)alloc((size_t)BTt * DD * 4);       // 16
  u16* z_bf   = (u16*)alloc((size_t)BTt * DD * 2);         // 8
  u16* WtX    = (u16*)alloc((size_t)2048 * 1024 * 2);      // 4
  u16* WtO    = (u16*)alloc((size_t)1024 * 512 * 2);       // 1
  u16* WtFF   = (u16*)alloc((size_t)8192 * 1024 * 2);      // 16 (col-interleaved Wff1|Wff3)
  u16* WtF2   = (u16*)alloc((size_t)1024 * 4096 * 2);      // 8
  float* prep = (float*)alloc((size_t)16 * NT * PREPSZ * 4);   // 36 MiB
  unsigned* masks = (unsigned*)alloc((size_t)16 * 64 * 64 * 4);  // 1 MiB

  // batched weight transposes (f32 -> bf16, Bt = [N,K] k-contiguous)
  {
    TransJobs J;
    J.src[0] = Wq;     J.dst[0] = WtX + (size_t)0 * 512 * 1024; J.K[0] = 1024; J.N[0] = 512;  J.rs[0] = 1; J.ro[0] = 0; J.lognx[0] = 4;
    J.src[1] = Wk;     J.dst[1] = WtX + (size_t)1 * 512 * 1024; J.K[1] = 1024; J.N[1] = 512;  J.rs[1] = 1; J.ro[1] = 0; J.lognx[1] = 4;
    J.src[2] = Wv;     J.dst[2] = WtX + (size_t)2 * 512 * 1024; J.K[2] = 1024; J.N[2] = 512;  J.rs[2] = 1; J.ro[2] = 0; J.lognx[2] = 4;
    J.src[3] = Wspike; J.dst[3] = WtX + (size_t)3 * 512 * 1024; J.K[3] = 1024; J.N[3] = 512;  J.rs[3] = 1; J.ro[3] = 0; J.lognx[3] = 4;
    J.src[4] = Wo;     J.dst[4] = WtO;                          J.K[4] = 512;  J.N[4] = 1024; J.rs[4] = 1; J.ro[4] = 0; J.lognx[4] = 5;
    J.src[5] = Wff1;   J.dst[5] = WtFF;                         J.K[5] = 1024; J.N[5] = 4096; J.rs[5] = 2; J.ro[5] = 0; J.lognx[5] = 7;
    J.src[6] = Wff3;   J.dst[6] = WtFF;                         J.K[6] = 1024; J.N[6] = 4096; J.rs[6] = 2; J.ro[6] = 1; J.lognx[6] = 7;
    J.src[7] = Wff2;   J.dst[7] = WtF2;                         J.K[7] = 4096; J.N[7] = 1024; J.rs[7] = 1; J.ro[7] = 0; J.lognx[7] = 5;
    J.off[0] = 0;    J.off[1] = 512;  J.off[2] = 1024; J.off[3] = 1536;
    J.off[4] = 2048; J.off[5] = 2560; J.off[6] = 6656; J.off[7] = 10752;
    ktransB<<<14848, 256, 0, stream>>>(J);
  }

  // front end
  krms<<<BTt, 256, 0, stream>>>(x, norm_in_w, h, 0);
  kconv<<<BTt * DD / 256, 256, 0, stream>>>(h, conv_w, conv_b, hc);

  // QKVD projection (MFMA) with fused q|k L2-normalize -> X1 f32 [4096,2048]
  kmfma<4><<<dim3(16, 32), 256, 0, stream>>>(
      hc, 1024, WtX, X1, 2048, BTt, 2048, 1024, nullptr, nullptr, nullptr);

  // batched skinny projections: au (hc@Wau,silu), bb (hc@Wbeta), u1 (x@Wu1,silu)
  {
    SJobs S;
    S.A[0] = hc; S.B[0] = Wau;   S.bias[0] = bau;   S.C[0] = au; S.N[0] = 64; S.act[0] = 1; S.abf[0] = 1;
    S.A[1] = hc; S.B[1] = Wbeta; S.bias[1] = bbeta; S.C[1] = bb; S.N[1] = 8;  S.act[1] = 0; S.abf[1] = 1;
    S.A[2] = x;  S.B[2] = Wu1;   S.bias[2] = bu1;   S.C[2] = u1; S.N[2] = 64; S.act[2] = 1; S.abf[2] = 0;
    kgemmS3<<<768, 256, 0, stream>>>(S);
  }
  kgemm<<<dim3(8, 64), 256, 0, stream>>>(au, 0, Wad, bad_, ab, BTt, HKk, 64, 0);

  klifA<<<BB * HH, 64, 0, stream>>>(X1 + 1536, 2048, masks);
  kprep<<<16 * NT, 64, 0, stream>>>(X1, ab, bb, asp, bsp, masks, prep);
  kscan2<<<16 * 16, 64, 0, stream>>>(prep, yat);
  kheadnorm<<<BTt * HH / 4, 256, 0, stream>>>(yat, hnw, yat_bf);

  // gate path (f32)
  kgemm<<<dim3(16, 64), 256, 0, stream>>>(u1, 0, Wu2, bu2, gate, BTt, DD, 64, 2);

  // y2 = x + (yat @ Wo) * gate   (MFMA, f32 out)
  kmfma<2><<<dim3(8, 32), 256, 0, stream>>>(
      yat_bf, 512, WtO, y2, 1024, BTt, 1024, 512, x, gate, nullptr);

  // FFN (MFMA); FFN1 fuses SwiGLU combine in epilogue -> f_bf [4096][4096] bf16
  krms<<<BTt, 256, 0, stream>>>(y2, ffw, z_bf, 1);
  kmfma<1><<<dim3(64, 32), 256, 0, stream>>>(
      z_bf, 1024, WtFF, f_bf, 4096, BTt, 8192, 1024, nullptr, nullptr, nullptr);
  kmfma<3><<<dim3(8, 32), 256, 0, stream>>>(
      f_bf, 4096, WtF2, d_out, 1024, BTt, 1024, 4096, nullptr, nullptr, y2);
}

// Round 11
// 801.576 us; speedup vs baseline: 1.2043x; 1.2043x over previous
//
#include <hip/hip_runtime.h>
#include <hip/hip_bf16.h>

#define BB 2
#define TT 2048
#define DD 1024
#define HH 8
#define HKk 512
#define BTt 4096   // BB*TT
#define CC 16      // chunk length
#define NT 128     // tiles per bh
#define PREPSZ 4608  // floats per (bh,tile) prep block (18 KiB)
// prep layout: K1 0 | Q1 1024 | KH2 2048 | BV 3072 | A15 4096 | GW 4160 | pad->4608

typedef unsigned short u16;
typedef __attribute__((ext_vector_type(8))) short bf16x8;
typedef __attribute__((ext_vector_type(4))) float f32x4;

__device__ __forceinline__ u16 f2bf(float v) {
  union { float f; unsigned u; } c; c.f = v;
  return (u16)((c.u + 0x7fffu + ((c.u >> 16) & 1u)) >> 16);  // RNE
}
__device__ __forceinline__ float bf2f(u16 v) {
  union { unsigned u; float f; } c; c.u = ((unsigned)v) << 16; return c.f;
}
__device__ __forceinline__ float sigm(float x) { return 1.f / (1.f + expf(-x)); }

// DPP lane exchange on the VALU pipe (no DS). Within each 16-lane row:
//   0xB1 = quad_perm[1,0,3,2]  (exact xor1)
//   0x4E = quad_perm[2,3,0,1]  (exact xor2)
//   0x141 = row_half_mirror    (side-crossing bijection for the "xor4" stage)
//   0x128 = row_ror:8          (exact xor8: (i+8)%16 == i^8)
template <int CTRL>
__device__ __forceinline__ float dppx(float x) {
  union { float f; int i; } c; c.f = x;
  c.i = __builtin_amdgcn_update_dpp(c.i, c.i, CTRL, 0xf, 0xf, false);
  return c.f;
}

// async global->LDS, 16B per lane; dest = lds_base + lane*16 (wave-linear)
__device__ __forceinline__ void gld16(const u16* g, u16* l) {
  __builtin_amdgcn_global_load_lds((const __attribute__((address_space(1))) void*)g,
                                   (__attribute__((address_space(3))) void*)l, 16, 0, 0);
}

// ---------- batched weight transpose + cast ----------
// dst[(n*rs+ro)*K + k] = f2bf(src[k*N+n]) for 8 jobs in one launch.
struct TransJobs {
  const float* src[8];
  u16* dst[8];
  int K[8], N[8], rs[8], ro[8], lognx[8];
  int off[8];  // block-offset of each job (ascending)
};
__global__ __launch_bounds__(256) void ktransB(TransJobs J) {
  __shared__ u16 t[32][33];
  int bid = blockIdx.x;
  int j = 0;
#pragma unroll
  for (int q = 1; q < 8; q++) j += (bid >= J.off[q]) ? 1 : 0;
  int local = bid - J.off[j];
  const float* src = J.src[j];
  u16* dst = J.dst[j];
  int K = J.K[j], N = J.N[j], rs = J.rs[j], ro = J.ro[j];
  int nxm = (1 << J.lognx[j]) - 1;
  int n0 = (local & nxm) * 32, k0 = (local >> J.lognx[j]) * 32;
  int tx = threadIdx.x & 31, ty0 = threadIdx.x >> 5;
#pragma unroll
  for (int i = 0; i < 32; i += 8)
    t[ty0 + i][tx] = f2bf(src[(size_t)(k0 + ty0 + i) * N + n0 + tx]);
  __syncthreads();
#pragma unroll
  for (int i = 0; i < 32; i += 8)
    dst[((size_t)(n0 + ty0 + i) * rs + ro) * K + k0 + tx] = t[tx][ty0 + i];
}

// ---------- RMS norm over 1024 cols ----------
__global__ __launch_bounds__(256) void krms(const float* __restrict__ x,
                                            const float* __restrict__ w,
                                            void* __restrict__ out, int obf) {
  size_t row = blockIdx.x;
  __shared__ float red[4];
  float vals[4];
  float s = 0.f;
#pragma unroll
  for (int i = 0; i < 4; i++) {
    vals[i] = x[row * DD + threadIdx.x + i * 256];
    s += vals[i] * vals[i];
  }
#pragma unroll
  for (int off = 32; off; off >>= 1) s += __shfl_xor(s, off);
  if ((threadIdx.x & 63) == 0) red[threadIdx.x >> 6] = s;
  __syncthreads();
  float tot = red[0] + red[1] + red[2] + red[3];
  float sc = rsqrtf(tot * (1.f / DD) + 1e-6f);
#pragma unroll
  for (int i = 0; i < 4; i++) {
    size_t idx = row * DD + threadIdx.x + i * 256;
    float vv = vals[i] * sc * w[threadIdx.x + i * 256];
    if (obf) ((u16*)out)[idx] = f2bf(vv);
    else ((float*)out)[idx] = vv;
  }
}

// ---------- causal depthwise conv (KW=4) + bias + SiLU: f32 -> bf16 ----------
__global__ __launch_bounds__(256) void kconv(const float* __restrict__ hin,
                                             const float* __restrict__ cw,
                                             const float* __restrict__ cb,
                                             u16* __restrict__ hout) {
  size_t i = (size_t)blockIdx.x * 256 + threadIdx.x;
  int d = (int)(i & 1023);
  int bt = (int)(i >> 10);
  int b = bt >> 11, t = bt & 2047;
  float acc = cb[d];
#pragma unroll
  for (int j = 0; j < 4; j++) {
    int tt = t - 3 + j;
    if (tt >= 0) acc += hin[(((size_t)(b * TT + tt)) << 10) + d] * cw[d * 4 + j];
  }
  hout[i] = f2bf(acc * sigm(acc));
}

// ---------- small f32-compute GEMM (64x64 tiles) ----------
__global__ __launch_bounds__(256) void kgemm(const void* __restrict__ A, int abf,
                                             const float* __restrict__ Bm,
                                             const float* __restrict__ bias,
                                             float* __restrict__ C,
                                             int M, int N, int K, int act) {
  __shared__ __align__(16) float As[16][64];
  __shared__ __align__(16) float Bs[16][64];
  int tid = threadIdx.x;
  int tx = tid & 15, ty = tid >> 4;
  int row0 = blockIdx.y * 64, col0 = blockIdx.x * 64;
  float acc[4][4] = {};
  for (int k0 = 0; k0 < K; k0 += 16) {
#pragma unroll
    for (int l = 0; l < 4; l++) {
      int e = tid * 4 + l;
      int m = e >> 4, kk = e & 15;
      int gr = row0 + m;
      size_t ai = (size_t)gr * K + k0 + kk;
      As[kk][m] = (gr < M) ? (abf ? bf2f(((const u16*)A)[ai]) : ((const float*)A)[ai]) : 0.f;
    }
#pragma unroll
    for (int l = 0; l < 4; l++) {
      int e = tid + l * 256;
      int kk = e >> 6, n = e & 63;
      int gc = col0 + n;
      Bs[kk][n] = (gc < N) ? Bm[(size_t)(k0 + kk) * N + gc] : 0.f;
    }
    __syncthreads();
#pragma unroll
    for (int kk = 0; kk < 16; kk++) {
      float4 av = *(const float4*)&As[kk][ty * 4];
      float4 bv = *(const float4*)&Bs[kk][tx * 4];
      float a[4] = {av.x, av.y, av.z, av.w};
      float b[4] = {bv.x, bv.y, bv.z, bv.w};
#pragma unroll
      for (int i = 0; i < 4; i++)
#pragma unroll
        for (int j = 0; j < 4; j++) acc[i][j] += a[i] * b[j];
    }
    __syncthreads();
  }
#pragma unroll
  for (int i = 0; i < 4; i++) {
    int r = row0 + ty * 4 + i;
    if (r >= M) continue;
#pragma unroll
    for (int j = 0; j < 4; j++) {
      int cc = col0 + tx * 4 + j;
      if (cc >= N) continue;
      float vv = acc[i][j];
      if (bias) vv += bias[cc];
      if (act == 1) vv = vv * sigm(vv);
      else if (act == 2) vv = sigm(vv);
      C[(size_t)r * N + cc] = vv;
    }
  }
}

// ---------- batched skinny-N GEMM: 3 jobs x 256 blocks, 16-row tiles ----------
struct SJobs {
  const void* A[3];
  const float* B[3];
  const float* bias[3];
  float* C[3];
  int N[3], act[3], abf[3];
};
__global__ __launch_bounds__(256) void kgemmS3(SJobs J) {
  __shared__ __align__(16) float As[32][17];
  __shared__ __align__(16) float Bs[32][64];
  int job = blockIdx.x >> 8;
  int row0 = (blockIdx.x & 255) << 4;
  const void* A = J.A[job];
  const float* Bm = J.B[job];
  int N = J.N[job], abf = J.abf[job], act = J.act[job];
  int tid = threadIdx.x;
  int tx = tid & 63;
  int ty = tid >> 6;
  float acc[4] = {};
  for (int k0 = 0; k0 < DD; k0 += 32) {
    __syncthreads();
#pragma unroll
    for (int l = 0; l < 2; l++) {
      int idx = tid * 2 + l;
      int k = idx & 31, m = idx >> 5;
      size_t ai = (size_t)(row0 + m) * DD + k0 + k;
      As[k][m] = abf ? bf2f(((const u16*)A)[ai]) : ((const float*)A)[ai];
    }
#pragma unroll
    for (int l = 0; l < 8; l++) {
      int idx = tid + l * 256;
      int n = idx & 63, k = idx >> 6;
      Bs[k][n] = (n < N) ? Bm[(size_t)(k0 + k) * N + n] : 0.f;
    }
    __syncthreads();
#pragma unroll
    for (int kk = 0; kk < 32; kk++) {
      float b = Bs[kk][tx];
#pragma unroll
      for (int i = 0; i < 4; i++) acc[i] += As[kk][ty * 4 + i] * b;
    }
  }
  if (tx < N) {
    float* C = J.C[job];
    const float* bias = J.bias[job];
#pragma unroll
    for (int i = 0; i < 4; i++) {
      float vv = acc[i] + bias[tx];
      if (act == 1) vv = vv * sigm(vv);
      C[(size_t)(row0 + ty * 4 + i) * N + tx] = vv;
    }
  }
}

// ---------- big MFMA GEMM: global_load_lds staging + XOR-swizzled LDS ----------
// EPI: 0 = f32 store | 1 = interleaved SwiGLU -> bf16 | 2 = g1+v*g2 | 3 = f1+v
//      4 = f32 store with per-64-col L2-normalize on cols<1024 (QKVD q|k)
template <int EPI>
__global__ __launch_bounds__(256) void kmfma(
    const u16* __restrict__ A, int lda, const u16* __restrict__ Bt,
    void* __restrict__ C, int ldc, int M, int N, int K,
    const float* __restrict__ g1f, const float* __restrict__ g2f,
    const float* __restrict__ f1) {
  __shared__ __align__(16) u16 As[128 * 64];
  __shared__ __align__(16) u16 Bs[128 * 64];
  int tid = threadIdx.x;
  int lane = tid & 63, wv = tid >> 6;
  int m0 = (wv & 1) * 64, n0 = (wv >> 1) * 64;
  int ml = lane & 15, kq = (lane >> 4) << 3;
  // XCD-aware block swizzle (grid sizes are all %8==0): contiguous work chunks
  // per XCD so neighboring tiles share L2-resident panels.
  int nbx = gridDim.x;
  int flat = blockIdx.y * nbx + blockIdx.x;
  int nwg = nbx * gridDim.y;
  int work = (flat & 7) * (nwg >> 3) + (flat >> 3);
  int row0 = (work / nbx) * 128, col0 = (work % nbx) * 128;
  int lrow = lane >> 3;             // 0..7 within 8-row band
  int lslot = (lane & 7) ^ lrow;    // pre-swizzled source 16B-slot

  f32x4 acc[4][4];
#pragma unroll
  for (int i = 0; i < 4; i++)
#pragma unroll
    for (int j = 0; j < 4; j++) acc[i][j] = (f32x4){0.f, 0.f, 0.f, 0.f};

  for (int k0 = 0; k0 < K; k0 += 64) {
    __syncthreads();
#pragma unroll
    for (int j = 0; j < 4; j++) {
      int r0 = j * 32 + wv * 8;
      gld16(&A[(size_t)(row0 + r0 + lrow) * lda + k0 + lslot * 8], &As[r0 * 64]);
      gld16(&Bt[(size_t)(col0 + r0 + lrow) * K + k0 + lslot * 8], &Bs[r0 * 64]);
    }
    __syncthreads();
#pragma unroll
    for (int kk = 0; kk < 64; kk += 32) {
      int sw = (((kk + kq) >> 3) ^ (ml & 7)) << 3;
      bf16x8 af[4], bfr[4];
#pragma unroll
      for (int i = 0; i < 4; i++)
        af[i] = *(const bf16x8*)&As[(m0 + i * 16 + ml) * 64 + sw];
#pragma unroll
      for (int j = 0; j < 4; j++)
        bfr[j] = *(const bf16x8*)&Bs[(n0 + j * 16 + ml) * 64 + sw];
#pragma unroll
      for (int i = 0; i < 4; i++)
#pragma unroll
        for (int j = 0; j < 4; j++)
          acc[i][j] = __builtin_amdgcn_mfma_f32_16x16x32_bf16(af[i], bfr[j], acc[i][j], 0, 0, 0);
    }
  }
  int rbase = row0 + m0 + ((lane >> 4) << 2);
  if (EPI == 4) {
    // q|k L2-normalize: each wave's 64-col span == one head's dk group.
    int donorm = (col0 + n0) < 1024;
#pragma unroll
    for (int i = 0; i < 4; i++) {
#pragma unroll
      for (int r = 0; r < 4; r++) {
        float s = 0.f;
#pragma unroll
        for (int j = 0; j < 4; j++) { float v = acc[i][j][r]; s += v * v; }
#pragma unroll
        for (int off = 1; off < 16; off <<= 1) s += __shfl_xor(s, off);
        float sc = donorm ? 1.f / (sqrtf(s) + 1e-6f) : 1.f;
        int gr = rbase + i * 16 + r;
#pragma unroll
        for (int j = 0; j < 4; j++) {
          int gc = col0 + n0 + j * 16 + ml;
          ((float*)C)[(size_t)gr * ldc + gc] = acc[i][j][r] * sc;
        }
      }
    }
    return;
  }
#pragma unroll
  for (int i = 0; i < 4; i++) {
#pragma unroll
    for (int j = 0; j < 4; j++) {
      int gc = col0 + n0 + j * 16 + ml;
#pragma unroll
      for (int r = 0; r < 4; r++) {
        int gr = rbase + i * 16 + r;
        float v = acc[i][j][r];
        if (EPI == 0) {
          ((float*)C)[(size_t)gr * ldc + gc] = v;
        } else if (EPI == 1) {
          // interleaved SwiGLU: even col = Wff1 (silu), odd col = Wff3.
          float p = __shfl_xor(v, 1);
          float a0 = (lane & 1) ? p : v;
          float b0 = (lane & 1) ? v : p;
          float g = a0 * sigm(a0) * b0;
          if (!(lane & 1))
            ((u16*)C)[(size_t)gr * ldc + (gc >> 1)] = f2bf(g);
        } else if (EPI == 2) {
          size_t idx = (size_t)gr * ldc + gc;
          ((float*)C)[idx] = g1f[idx] + v * g2f[idx];
        } else {
          size_t idx = (size_t)gr * ldc + gc;
          ((float*)C)[idx] = f1[idx] + v;
        }
      }
    }
  }
}

// ---------- headwise RMS norm: yat f32 -> bf16 ----------
__global__ __launch_bounds__(256) void kheadnorm(const float* __restrict__ y,
                                                 const float* __restrict__ hw,
                                                 u16* __restrict__ yo) {
  int lane = threadIdx.x & 63;
  size_t r = (size_t)blockIdx.x * 4 + (threadIdx.x >> 6);
  int h = (int)(r & 7);
  float vv = y[r * 64 + lane];
  float s = vv * vv;
#pragma unroll
  for (int off = 32; off; off >>= 1) s += __shfl_xor(s, off);
  yo[r * 64 + lane] = f2bf(vv * rsqrtf(s * (1.f / 64.f) + 1e-6f) * hw[h * 64 + lane]);
}

// ---------- klifA: membrane recurrence only -> packed spike bitmasks ----------
__global__ __launch_bounds__(64) void klifA(const float* __restrict__ dr, int drs,
                                            unsigned* __restrict__ masks) {
  int bh = blockIdx.x;
  int b = bh >> 3, h = bh & 7;
  int lane = threadIdx.x;
  float cur[32], nxt[32];
#pragma unroll
  for (int i = 0; i < 32; i++)
    cur[i] = dr[(size_t)(b * TT + i) * drs + h * 64 + lane];
  float mem = 0.f;
  for (int t0 = 0; t0 < TT; t0 += 32) {
    if (t0 + 32 < TT) {
#pragma unroll
      for (int i = 0; i < 32; i++)
        nxt[i] = dr[(size_t)(b * TT + t0 + 32 + i) * drs + h * 64 + lane];
    }
    unsigned m = 0;
#pragma unroll
    for (int i = 0; i < 32; i++) {
      mem = 0.9f * mem + cur[i];
      int s = (mem > 0.5f) ? 1 : 0;
      mem -= s ? 0.5f : 0.f;
      m |= ((unsigned)s) << i;
    }
    masks[((size_t)bh * 64 + (t0 >> 5)) * 64 + lane] = m;
#pragma unroll
    for (int i = 0; i < 32; i++) cur[i] = nxt[i];
  }
}

// ---------- kprep: chunk C=16 UT-transform precompute + fused LIF gates ----------
// klifB fused in: per t, spike bit from masks, __ballot over the 64 k-lanes
// for `active`, 6-shuffle reduce for the beta term. bet[] is wave-uniform;
// lane 0 writes sBeta with STATIC indices (rule #20: no dynamic reg indexing).
// LDS leading dim padded 64->68: phase-2 reads sKiP[s2][k] across the 16 s2
// lanes hit banks (s2*4+k)%32 -> 2-way max (was 16-way at stride 64).
__global__ __launch_bounds__(64) void kprep(const float* __restrict__ X1,
                                            const float* __restrict__ ab,
                                            const float* __restrict__ bb,
                                            const float* __restrict__ asp,
                                            const float* __restrict__ bsp,
                                            const unsigned* __restrict__ masks,
                                            float* __restrict__ prep) {
  int blk = blockIdx.x;          // 16 bh * 128 tiles
  int bh = blk >> 7, T = blk & 127;
  int b = bh >> 3, h = bh & 7;
  int lane = threadIdx.x;
  size_t row0 = (size_t)(b * TT) + (size_t)T * CC;
  float* out = prep + (size_t)blk * PREPSZ;
  __shared__ float sKP[CC][68], sKiP[CC][68], sQP[CC][68];
  __shared__ float sBC[CC * CC], sG[CC * CC], sW[CC * CC], sBeta[CC];

  float aspk = asp[h * 64 + lane];
  float bspk = bsp[h * 64 + lane];
  float Pt[CC], kv[CC], kh[CC], bet[CC];
  {
    float P = 1.f;
#pragma unroll
    for (int t = 0; t < CC; t++) {
      size_t rt = row0 + t;
      int tg = T * CC + t;
      unsigned mw = masks[((size_t)bh * 64 + (tg >> 5)) * 64 + lane];
      int s = (mw >> (tg & 31)) & 1;
      unsigned long long act = __ballot(s != 0);
      float sp = (float)s;
      float abv = ab[rt * HKk + h * 64 + lane];
      int active = (act != 0ull);
      float a = active ? sigm(abv + aspk * sp) : 1.f;
      float r2 = sp * bspk;
#pragma unroll
      for (int off = 32; off; off >>= 1) r2 += __shfl_xor(r2, off);
      float bbv = bb[rt * HH + h];
      bet[t] = active ? sigm(bbv + r2) : 0.f;
      kv[t] = X1[rt * 2048 + h * 64 + 512 + lane];
      float qv = X1[rt * 2048 + h * 64 + lane];
      P *= a;
      Pt[t] = P;
      float qp = qv * P;
      sQP[t][lane] = qp;
      out[1024 + t * 64 + lane] = qp;  // Q1
    }
    float PC = Pt[CC - 1];
#pragma unroll
    for (int t = 0; t < CC; t++) {
      float KiPv = kv[t] / Pt[t];
      sKP[t][lane] = kv[t] * Pt[t];
      sKiP[t][lane] = KiPv;
      kh[t] = PC * KiPv;
    }
    out[4096 + lane] = PC;  // A15
  }
  if (lane == 0) {
#pragma unroll
    for (int t = 0; t < CC; t++) sBeta[t] = bet[t];
  }
  __syncthreads();
#pragma unroll
  for (int t = 0; t < CC; t++) out[t * 64 + lane] = bet[t] * kv[t] * Pt[t];  // K1

  // phase 2: 256 (t,s) pairs, 4 per lane
#pragma unroll
  for (int i = 0; i < 4; i++) {
    int p = lane + 64 * i;
    int t2 = p >> 4, s2 = p & 15;
    float ac = 0.f, ag = 0.f;
#pragma unroll
    for (int k = 0; k < 64; k++) {
      float kip = sKiP[s2][k];
      ac += sKP[t2][k] * kip;
      ag += sQP[t2][k] * kip;
    }
    sBC[p] = (t2 > s2) ? sBeta[t2] * ac : 0.f;
    sG[p] = (t2 >= s2) ? ag : 0.f;
    sW[p] = 0.f;
  }
  __syncthreads();
  if (lane < CC) sW[lane * CC + lane] = 1.f;
  __syncthreads();

  // phase 3a: W = (I + strictlower(BC))^{-1}, forward substitution
  for (int t = 1; t < CC; t++) {
    if (lane < t) {
      float a = -sBC[t * CC + lane];
      for (int s = lane + 1; s < t; s++) a -= sBC[t * CC + s] * sW[s * CC + lane];
      sW[t * CC + lane] = a;
    }
    __syncthreads();
  }
  // phase 3b: GW = G * W (lower incl diag), 4 entries per lane
#pragma unroll
  for (int i = 0; i < 4; i++) {
    int p = lane + 64 * i;
    int t2 = p >> 4, s2 = p & 15;
    float gw = 0.f;
    if (s2 <= t2)
      for (int m = s2; m <= t2; m++) gw += sG[t2 * CC + m] * sW[m * CC + s2];
    out[4160 + p] = gw;
  }
  // phase 4: KH2_r = sum_{s>=r} kh_s * W[s][r]   (lane = k)
#pragma unroll
  for (int r = 0; r < CC; r++) {
    float acc = 0.f;
    for (int s = r; s < CC; s++) acc += kh[s] * sW[s * CC + r];
    out[2048 + r * 64 + lane] = acc;
  }
  // phase 5: BV_t = beta_t * v_t
#pragma unroll
  for (int t = 0; t < CC; t++)
    out[3072 + t * 64 + lane] = bet[t] * X1[(row0 + t) * 2048 + h * 64 + 1024 + lane];
}

// ---------- kscan2 v5 (FINAL): no-LDS, no-DS chunk walker (DPP exchanges) ----------
// 256 single-wave blocks = vg(16) x bh(16); bh=bid&15 pins one bh's blocks to
// one XCD so prep is L2-resident. Global->reg with 1-tile-ahead prefetch; all
// 45 per-tile lane exchanges on the VALU via DPP (quad_perm/half_mirror/ror8).
// Measured 164 us. Attempts past this all regressed:
//  r5: v-split 2 waves/CU -> 193 (DS-pipe contention, pre-DPP)
//  r8: asm keep-alive reg-pin -> 180 (compiler rematerializes loads anyway)
//  r9: K-split 2 waves/CU on DPP -> 190 (per-tile stall-bound, TLP no help)
//  r10: LDS ping-pong staging -> 330 (vmcnt+lgkmcnt both on critical path)
// The serial S->dot->butterfly->u->S chain w/ ~160 L2 loads/tile is the floor
// for this decomposition at HIP source level.
__global__ __launch_bounds__(64, 1) void kscan2(const float* __restrict__ prep,
                                                float* __restrict__ y) {
  int bid = blockIdx.x;
  int bh = bid & 15, vg = bid >> 4;
  int b = bh >> 3, h = bh & 7;
  int lane = threadIdx.x;
  int kp = lane & 15, vv = lane >> 4;
  const float* base = prep + (size_t)bh * NT * PREPSZ;

  float4 S = make_float4(0.f, 0.f, 0.f, 0.f);
  float4 k1A[16], q1A[16], k1B[16], q1B[16];
#pragma unroll
  for (int t = 0; t < CC; t++) {
    k1A[t] = *(const float4*)(base + t * 64 + kp * 4);
    q1A[t] = *(const float4*)(base + 1024 + t * 64 + kp * 4);
  }
  size_t yb = (size_t)(b * TT) * HKk + h * 64 + vg * 4 + vv;

#define TILEBODY(TI, K1, Q1, K1N, Q1N)                                          \
  do {                                                                          \
    const float* bp = base + (size_t)(TI)*PREPSZ;                               \
    int TN = ((TI) + 1 < NT) ? (TI) + 1 : NT - 1;                               \
    const float* np = base + (size_t)TN * PREPSZ;                               \
    /* early loads for this tile's tail (L2 latency hides under dot+dpp) */     \
    float4 kh2[16], gw[4], a15;                                                 \
    float bvs;                                                                  \
    _Pragma("unroll") for (int r = 0; r < CC; r++)                              \
        kh2[r] = *(const float4*)(bp + 2048 + r * 64 + kp * 4);                 \
    a15 = *(const float4*)(bp + 4096 + kp * 4);                                 \
    _Pragma("unroll") for (int i = 0; i < 4; i++)                               \
        gw[i] = *(const float4*)(bp + 4160 + kp * 16 + i * 4);                  \
    bvs = bp[3072 + kp * 64 + vg * 4 + vv];                                     \
    /* dot: partials over this lane's 4 k-entries */                            \
    float bt[16], qb[16];                                                       \
    _Pragma("unroll") for (int t = 0; t < CC; t++) {                            \
      bt[t] = K1[t].x * S.x + K1[t].y * S.y + K1[t].z * S.z + K1[t].w * S.w;    \
      qb[t] = Q1[t].x * S.x + Q1[t].y * S.y + Q1[t].z * S.z + Q1[t].w * S.w;    \
    }                                                                           \
    /* prefetch next tile's K1/Q1 */                                            \
    _Pragma("unroll") for (int t = 0; t < CC; t++) {                            \
      K1N[t] = *(const float4*)(np + t * 64 + kp * 4);                          \
      Q1N[t] = *(const float4*)(np + 1024 + t * 64 + kp * 4);                   \
    }                                                                           \
    /* reduce-scatter bt: lane kp -> full bt[kp] (DPP stages 8,hm,2,1) */       \
    float b8[8], b4[4], b2[2], bS;                                              \
    _Pragma("unroll") for (int j = 0; j < 8; j++) {                             \
      float snd = (kp & 8) ? bt[j] : bt[j + 8];                                 \
      float rcv = dppx<0x128>(snd);                                             \
      b8[j] = ((kp & 8) ? bt[j + 8] : bt[j]) + rcv;                             \
    }                                                                           \
    _Pragma("unroll") for (int j = 0; j < 4; j++) {                             \
      float snd = (kp & 4) ? b8[j] : b8[j + 4];                                 \
      float rcv = dppx<0x141>(snd);                                             \
      b4[j] = ((kp & 4) ? b8[j + 4] : b8[j]) + rcv;                             \
    }                                                                           \
    _Pragma("unroll") for (int j = 0; j < 2; j++) {                             \
      float snd = (kp & 2) ? b4[j] : b4[j + 2];                                 \
      float rcv = dppx<0x4E>(snd);                                              \
      b2[j] = ((kp & 2) ? b4[j + 2] : b4[j]) + rcv;                             \
    }                                                                           \
    {                                                                           \
      float snd = (kp & 1) ? b2[0] : b2[1];                                     \
      float rcv = dppx<0xB1>(snd);                                              \
      bS = ((kp & 1) ? b2[1] : b2[0]) + rcv;                                    \
    }                                                                           \
    float uS = bvs - bS;                                                        \
    /* all-gather uS -> u[0..15] in natural order (DPP stages 1,2,hm,8) */      \
    float u[16];                                                                \
    {                                                                           \
      float g = dppx<0xB1>(uS);                                                 \
      float a0 = (kp & 1) ? g : uS, a1 = (kp & 1) ? uS : g;                     \
      float g0 = dppx<0x4E>(a0), g1 = dppx<0x4E>(a1);                           \
      float c0 = (kp & 2) ? g0 : a0, c1 = (kp & 2) ? g1 : a1;                   \
      float c2 = (kp & 2) ? a0 : g0, c3 = (kp & 2) ? a1 : g1;                   \
      float h0 = dppx<0x141>(c0), h1 = dppx<0x141>(c1);                         \
      float h2 = dppx<0x141>(c2), h3 = dppx<0x141>(c3);                         \
      float d0 = (kp & 4) ? h0 : c0, d1 = (kp & 4) ? h1 : c1;                   \
      float d2 = (kp & 4) ? h2 : c2, d3 = (kp & 4) ? h3 : c3;                   \
      float d4 = (kp & 4) ? c0 : h0, d5 = (kp & 4) ? c1 : h1;                   \
      float d6 = (kp & 4) ? c2 : h2, d7 = (kp & 4) ? c3 : h3;                   \
      float e0 = dppx<0x128>(d0), e1 = dppx<0x128>(d1);                         \
      float e2 = dppx<0x128>(d2), e3 = dppx<0x128>(d3);                         \
      float e4 = dppx<0x128>(d4), e5 = dppx<0x128>(d5);                         \
      float e6 = dppx<0x128>(d6), e7 = dppx<0x128>(d7);                         \
      u[0] = (kp & 8) ? e0 : d0; u[1] = (kp & 8) ? e1 : d1;                     \
      u[2] = (kp & 8) ? e2 : d2; u[3] = (kp & 8) ? e3 : d3;                     \
      u[4] = (kp & 8) ? e4 : d4; u[5] = (kp & 8) ? e5 : d5;                     \
      u[6] = (kp & 8) ? e6 : d6; u[7] = (kp & 8) ? e7 : d7;                     \
      u[8] = (kp & 8) ? d0 : e0; u[9] = (kp & 8) ? d1 : e1;                     \
      u[10] = (kp & 8) ? d2 : e2; u[11] = (kp & 8) ? d3 : e3;                   \
      u[12] = (kp & 8) ? d4 : e4; u[13] = (kp & 8) ? d5 : e5;                   \
      u[14] = (kp & 8) ? d6 : e6; u[15] = (kp & 8) ? d7 : e7;                   \
    }                                                                           \
    /* reduce-scatter qb -> qsel = full qb[kp] (DPP) */                         \
    float p8[8], p4[4], p2[2], qsel;                                            \
    _Pragma("unroll") for (int j = 0; j < 8; j++) {                             \
      float snd = (kp & 8) ? qb[j] : qb[j + 8];                                 \
      float rcv = dppx<0x128>(snd);                                             \
      p8[j] = ((kp & 8) ? qb[j + 8] : qb[j]) + rcv;                             \
    }                                                                           \
    _Pragma("unroll") for (int j = 0; j < 4; j++) {                             \
      float snd = (kp & 4) ? p8[j] : p8[j + 4];                                 \
      float rcv = dppx<0x141>(snd);                                             \
      p4[j] = ((kp & 4) ? p8[j + 4] : p8[j]) + rcv;                             \
    }                                                                           \
    _Pragma("unroll") for (int j = 0; j < 2; j++) {                             \
      float snd = (kp & 2) ? p4[j] : p4[j + 2];                                 \
      float rcv = dppx<0x4E>(snd);                                              \
      p2[j] = ((kp & 2) ? p4[j + 2] : p4[j]) + rcv;                             \
    }                                                                           \
    {                                                                           \
      float snd = (kp & 1) ? p2[0] : p2[1];                                     \
      float rcv = dppx<0xB1>(snd);                                              \
      qsel = ((kp & 1) ? p2[1] : p2[0]) + rcv;                                  \
    }                                                                           \
    /* output row t=kp (GW upper triangle is zero from kprep) */                \
    float o = qsel;                                                             \
    _Pragma("unroll") for (int i = 0; i < 4; i++)                               \
        o += gw[i].x * u[i * 4] + gw[i].y * u[i * 4 + 1] +                      \
             gw[i].z * u[i * 4 + 2] + gw[i].w * u[i * 4 + 3];                   \
    y[yb + (size_t)((TI)*CC + kp) * HKk] = o;                                   \
    /* state update: S = A15 .* S + sum_r KH2[r] * u[r] */                      \
    S.x *= a15.x; S.y *= a15.y; S.z *= a15.z; S.w *= a15.w;                     \
    _Pragma("unroll") for (int r = 0; r < CC; r++) {                            \
      S.x += kh2[r].x * u[r]; S.y += kh2[r].y * u[r];                           \
      S.z += kh2[r].z * u[r]; S.w += kh2[r].w * u[r];                           \
    }                                                                           \
  } while (0)

  for (int T = 0; T < NT; T += 2) {
    TILEBODY(T, k1A, q1A, k1B, q1B);
    TILEBODY(T + 1, k1B, q1B, k1A, q1A);
  }
#undef TILEBODY
}

extern "C" void kernel_launch(void* const* d_in, const int* in_sizes, int n_in,
                              void* d_out, int out_size, void* d_ws, size_t ws_size,
                              hipStream_t stream) {
  const float *x = (const float*)d_in[0], *norm_in_w = (const float*)d_in[1],
              *conv_w = (const float*)d_in[2], *conv_b = (const float*)d_in[3],
              *Wq = (const float*)d_in[4], *Wk = (const float*)d_in[5],
              *Wv = (const float*)d_in[6], *Wo = (const float*)d_in[7],
              *Wspike = (const float*)d_in[8], *Wau = (const float*)d_in[9],
              *bau = (const float*)d_in[10], *Wad = (const float*)d_in[11],
              *bad_ = (const float*)d_in[12], *asp = (const float*)d_in[13],
              *Wbeta = (const float*)d_in[14], *bbeta = (const float*)d_in[15],
              *bsp = (const float*)d_in[16], *hnw = (const float*)d_in[17],
              *Wu1 = (const float*)d_in[18], *bu1 = (const float*)d_in[19],
              *Wu2 = (const float*)d_in[20], *bu2 = (const float*)d_in[21],
              *ffw = (const float*)d_in[22], *Wff1 = (const float*)d_in[23],
              *Wff3 = (const float*)d_in[24], *Wff2 = (const float*)d_in[25];
  (void)in_sizes; (void)n_in; (void)out_size; (void)ws_size;

  char* wsb = (char*)d_ws;
  size_t off = 0;
  auto alloc = [&](size_t bytes) {
    void* p = wsb + off;
    off += (bytes + 255) & ~(size_t)255;
    return p;
  };
  float* h    = (float*)alloc((size_t)BTt * DD * 4);       // 16 MiB
  u16*   hc   = (u16*)alloc((size_t)BTt * DD * 2);         // 8
  size_t qoff = off;  // overlay region start (dead before FFN)
  float* X1   = (float*)alloc((size_t)BTt * 2048 * 4);     // 32  q|k|v|drive
  float* ab   = (float*)alloc((size_t)BTt * HKk * 4);      // 8
  float* au   = (float*)alloc((size_t)BTt * 64 * 4);       // 1
  float* bb   = (float*)alloc((size_t)BTt * HH * 4);       // .125
  float* u1   = (float*)alloc((size_t)BTt * 64 * 4);       // 1
  float* gate = (float*)alloc((size_t)BTt * DD * 4);       // 16
  float* yat  = (float*)alloc((size_t)BTt * HKk * 4);      // 8
  u16* yat_bf = (u16*)alloc((size_t)BTt * HKk * 2);        // 4
  u16* f_bf   = (u16*)(wsb + qoff);  // 32 MiB overlay over X1 (dead at FFN)
  float* y2   = (float*)alloc((size_t)BTt * DD * 4);       // 16
  u16* z_bf   = (u16*)alloc((size_t)BTt * DD * 2);         // 8
  u16* WtX    = (u16*)alloc((size_t)2048 * 1024 * 2);      // 4
  u16* WtO    = (u16*)alloc((size_t)1024 * 512 * 2);       // 1
  u16* WtFF   = (u16*)alloc((size_t)8192 * 1024 * 2);      // 16 (col-interleaved Wff1|Wff3)
  u16* WtF2   = (u16*)alloc((size_t)1024 * 4096 * 2);      // 8
  float* prep = (float*)alloc((size_t)16 * NT * PREPSZ * 4);   // 36 MiB
  unsigned* masks = (unsigned*)alloc((size_t)16 * 64 * 64 * 4);  // 1 MiB

  // batched weight transposes (f32 -> bf16, Bt = [N,K] k-contiguous)
  {
    TransJobs J;
    J.src[0] = Wq;     J.dst[0] = WtX + (size_t)0 * 512 * 1024; J.K[0] = 1024; J.N[0] = 512;  J.rs[0] = 1; J.ro[0] = 0; J.lognx[0] = 4;
    J.src[1] = Wk;     J.dst[1] = WtX + (size_t)1 * 512 * 1024; J.K[1] = 1024; J.N[1] = 512;  J.rs[1] = 1; J.ro[1] = 0; J.lognx[1] = 4;
    J.src[2] = Wv;     J.dst[2] = WtX + (size_t)2 * 512 * 1024; J.K[2] = 1024; J.N[2] = 512;  J.rs[2] = 1; J.ro[2] = 0; J.lognx[2] = 4;
    J.src[3] = Wspike; J.dst[3] = WtX + (size_t)3 * 512 * 1024; J.K[3] = 1024; J.N[3] = 512;  J.rs[3] = 1; J.ro[3] = 0; J.lognx[3] = 4;
    J.src[4] = Wo;     J.dst[4] = WtO;                          J.K[4] = 512;  J.N[4] = 1024; J.rs[4] = 1; J.ro[4] = 0; J.lognx[4] = 5;
    J.src[5] = Wff1;   J.dst[5] = WtFF;                         J.K[5] = 1024; J.N[5] = 4096; J.rs[5] = 2; J.ro[5] = 0; J.lognx[5] = 7;
    J.src[6] = Wff3;   J.dst[6] = WtFF;                         J.K[6] = 1024; J.N[6] = 4096; J.rs[6] = 2; J.ro[6] = 1; J.lognx[6] = 7;
    J.src[7] = Wff2;   J.dst[7] = WtF2;                         J.K[7] = 4096; J.N[7] = 1024; J.rs[7] = 1; J.ro[7] = 0; J.lognx[7] = 5;
    J.off[0] = 0;    J.off[1] = 512;  J.off[2] = 1024; J.off[3] = 1536;
    J.off[4] = 2048; J.off[5] = 2560; J.off[6] = 6656; J.off[7] = 10752;
    ktransB<<<14848, 256, 0, stream>>>(J);
  }

  // front end
  krms<<<BTt, 256, 0, stream>>>(x, norm_in_w, h, 0);
  kconv<<<BTt * DD / 256, 256, 0, stream>>>(h, conv_w, conv_b, hc);

  // QKVD projection (MFMA) with fused q|k L2-normalize -> X1 f32 [4096,2048]
  kmfma<4><<<dim3(16, 32), 256, 0, stream>>>(
      hc, 1024, WtX, X1, 2048, BTt, 2048, 1024, nullptr, nullptr, nullptr);

  // batched skinny projections: au (hc@Wau,silu), bb (hc@Wbeta), u1 (x@Wu1,silu)
  {
    SJobs S;
    S.A[0] = hc; S.B[0] = Wau;   S.bias[0] = bau;   S.C[0] = au; S.N[0] = 64; S.act[0] = 1; S.abf[0] = 1;
    S.A[1] = hc; S.B[1] = Wbeta; S.bias[1] = bbeta; S.C[1] = bb; S.N[1] = 8;  S.act[1] = 0; S.abf[1] = 1;
    S.A[2] = x;  S.B[2] = Wu1;   S.bias[2] = bu1;   S.C[2] = u1; S.N[2] = 64; S.act[2] = 1; S.abf[2] = 0;
    kgemmS3<<<768, 256, 0, stream>>>(S);
  }
  kgemm<<<dim3(8, 64), 256, 0, stream>>>(au, 0, Wad, bad_, ab, BTt, HKk, 64, 0);

  klifA<<<BB * HH, 64, 0, stream>>>(X1 + 1536, 2048, masks);
  kprep<<<16 * NT, 64, 0, stream>>>(X1, ab, bb, asp, bsp, masks, prep);
  kscan2<<<16 * 16, 64, 0, stream>>>(prep, yat);
  kheadnorm<<<BTt * HH / 4, 256, 0, stream>>>(yat, hnw, yat_bf);

  // gate path (f32)
  kgemm<<<dim3(16, 64), 256, 0, stream>>>(u1, 0, Wu2, bu2, gate, BTt, DD, 64, 2);

  // y2 = x + (yat @ Wo) * gate   (MFMA, f32 out)
  kmfma<2><<<dim3(8, 32), 256, 0, stream>>>(
      yat_bf, 512, WtO, y2, 1024, BTt, 1024, 512, x, gate, nullptr);

  // FFN (MFMA); FFN1 fuses SwiGLU combine in epilogue -> f_bf [4096][4096] bf16
  krms<<<BTt, 256, 0, stream>>>(y2, ffw, z_bf, 1);
  kmfma<1><<<dim3(64, 32), 256, 0, stream>>>(
      z_bf, 1024, WtFF, f_bf, 4096, BTt, 8192, 1024, nullptr, nullptr, nullptr);
  kmfma<3><<<dim3(8, 32), 256, 0, stream>>>(
      f_bf, 4096, WtF2, d_out, 1024, BTt, 1024, 4096, nullptr, nullptr, y2);
}